// Round 8
// baseline (553.014 us; speedup 1.0000x reference)
//
#include <hip/hip_runtime.h>
#include <math.h>

#define ALIGN16 __attribute__((aligned(16)))

__device__ __forceinline__ float rcpf_(float x){ return __builtin_amdgcn_rcpf(x); }
__device__ __forceinline__ float tanh_e(float x){
  float t = __expf(2.0f*x);
  return (t - 1.0f) * rcpf_(t + 1.0f);
}
__device__ __forceinline__ float sigm(float x){
  return rcpf_(1.0f + __expf(-x));
}

// 256 threads (4 waves, 1 wave/SIMD) per batch element; 256 blocks, 1/CU.
// __launch_bounds__(256,1) is the ONLY config this toolchain grants the full
// 512-reg unified VGPR+AGPR budget (R1: 236 arch VGPR + AGPR, zero mem spills;
// every 512/1024-thread variant was pinned to 128/64 and spilled 90-400MB).
// All big operands REGISTER-resident per thread: eKr[256], eRr[64], P[64]
// (encoder); XMr[64], dRr[64] (decoder). 4 barriers/step: A | C | z | update.
// Algebra: tanh(hs+xp) via E*P (E=exp(2hs) per step, P=exp(2xp) invariant),
// sum_u v*tanh = vsum - 2*sum v*rcp(E*P+1); softmax without max-sub
// (scores bounded); 1/S deferred into z; decoder fc layer folded:
// XMr[t] = sum_e xenc[t][e] * (fcW_ctx @ dK)[e][k], y_tilde phase eliminated.
// R8 fix vs R7: decoder invS factors. The xor{4,8,16,32} reduce sums each of
// the wave's 16 distinct t' ONCE (quad copies at bits 0-1 never added), so
// Sr == S already; the stale 0.25 factor scaled context by 4 (absmax 1.2e-3).
__global__ __launch_bounds__(256, 1)
void darnn_fused(const float* __restrict__ gin,   // [256][64][256]
                 const float* __restrict__ eKg,   // [256][256]
                 const float* __restrict__ eRg,   // [64][256]
                 const float* __restrict__ ebg,   // [256]
                 const float* __restrict__ dKg,   // [64][256]
                 const float* __restrict__ dRg,   // [64][256]
                 const float* __restrict__ dbg,   // [256]
                 const float* __restrict__ aeW,   // [192][64]
                 const float* __restrict__ aeb,   // [64]
                 const float* __restrict__ aev,   // [64]
                 const float* __restrict__ adW,   // [192][64]
                 const float* __restrict__ adb,   // [64]
                 const float* __restrict__ adv,   // [64]
                 const float* __restrict__ fcW,   // [65][64]
                 const float* __restrict__ fcb,   // [64]
                 const float* __restrict__ fcfW,  // [128][256]
                 const float* __restrict__ fcfb,  // [256]
                 float* __restrict__ out)         // [256][256]
{
  __shared__ ALIGN16 float s_w[4160];      // We_x -> Wd_x -> fcW(65x64)
  __shared__ ALIGN16 float s_xenc[64*68];  // x_encoded, row stride 68 (16B-aligned)
  __shared__ ALIGN16 float s_ag[256];      // activated gates
  __shared__ ALIGN16 float s_xtld[256];    // unnormalized x_tilde
  __shared__ ALIGN16 float s_hs[64];       // E_u = exp(2*preact_u)
  __shared__ ALIGN16 float s_pe[64];       // decoder unnorm softmax
  __shared__ ALIGN16 float s_redB[4];      // per-wave softmax partials
  __shared__ ALIGN16 float s_ctx[64];
  __shared__ ALIGN16 float s_yprev[64];
  __shared__ ALIGN16 float s_h[64];        // h (enc) / d (dec)
  __shared__ ALIGN16 float s_c[64];        // c (enc) / c' (dec)
  __shared__ ALIGN16 float s_aev[64];

  const int tid  = threadIdx.x;   // 0..255 = f = k
  const int lane = tid & 63;
  const int wv   = tid >> 6;      // 0..3
  const int u4   = tid >> 2;      // 0..63  (A-phase u, dec-C t')
  const int g4   = tid & 3;       // j/u/t slice
  const int b    = blockIdx.x;
  const float* inb = gin + (size_t)b * (64*256);

  // ================= encoder prologue =================
  for (int i = tid; i < 4096; i += 256) s_w[i] = aeW[8192 + i];   // We_x
  if (tid < 64) { s_aev[tid] = aev[tid]; s_h[tid] = 0.f; s_c[tid] = 0.f; }
  __syncthreads();

  // P[u] = exp(2 * x_proj[f=tid][u])  (step-invariant, 64 regs)
  float P[64];
#pragma unroll
  for (int i = 0; i < 64; ++i) P[i] = 0.f;
  for (int t = 0; t < 64; ++t) {
    float xv = inb[t*256 + tid];
#pragma unroll
    for (int q = 0; q < 16; ++q) {
      float4 w = *(const float4*)&s_w[t*64 + q*4];
      P[q*4+0] = fmaf(xv, w.x, P[q*4+0]);
      P[q*4+1] = fmaf(xv, w.y, P[q*4+1]);
      P[q*4+2] = fmaf(xv, w.z, P[q*4+2]);
      P[q*4+3] = fmaf(xv, w.w, P[q*4+3]);
    }
  }
#pragma unroll
  for (int i = 0; i < 64; ++i) P[i] = __expf(2.0f*P[i]);
  float vsum = 0.f;
#pragma unroll
  for (int q = 0; q < 16; ++q) {
    float4 v = *(const float4*)&s_aev[q*4];
    vsum += (v.x + v.y) + (v.z + v.w);
  }

  // register-resident weights (budget: 512 unified regs/thread at 1 wave/EU)
  float eKr[256];
#pragma unroll
  for (int q = 0; q < 256; ++q) eKr[q] = eKg[q*256 + tid];
  float eRr[64];
#pragma unroll
  for (int j = 0; j < 64; ++j) eRr[j] = eRg[j*256 + tid];
  float wh[16], wsr[16];
#pragma unroll
  for (int jj = 0; jj < 16; ++jj) {
    wh[jj]  = aeW[(g4*16 + jj)*64 + u4];        // We_h[j][u4]
    wsr[jj] = aeW[(64 + g4*16 + jj)*64 + u4];   // We_s[j][u4]
  }
  const float aeb_u = aeb[u4];
  const float eb_k  = ebg[tid];

  // ================= encoder loop (4 barriers/step) =================
  for (int t = 0; t < 64; ++t) {
    float xtv = inb[t*256 + tid];
    // A: E_u = exp(2*(h@We_h + c@We_s + b)[u]), (u=u4, j-slice g4*16..+16)
    float p0 = 0.f, p1 = 0.f;
#pragma unroll
    for (int q = 0; q < 4; ++q) {
      float4 h4 = *(const float4*)&s_h[g4*16 + q*4];
      float4 c4 = *(const float4*)&s_c[g4*16 + q*4];
      p0 = fmaf(h4.x, wh[q*4+0], p0);  p0 = fmaf(h4.y, wh[q*4+1], p0);
      p0 = fmaf(h4.z, wh[q*4+2], p0);  p0 = fmaf(h4.w, wh[q*4+3], p0);
      p1 = fmaf(c4.x, wsr[q*4+0], p1); p1 = fmaf(c4.y, wsr[q*4+1], p1);
      p1 = fmaf(c4.z, wsr[q*4+2], p1); p1 = fmaf(c4.w, wsr[q*4+3], p1);
    }
    float p = p0 + p1;
    p += __shfl_xor(p, 1); p += __shfl_xor(p, 2);
    float E = __expf(2.0f*(p + aeb_u));
    if (g4 == 0) s_hs[u4] = E;
    __syncthreads();  // b1

    // C: sc = vsum - 2*sum_u v_u*rcp(E_u*P_u+1); softmax w/o max-sub
    float sA = 0.f, sB = 0.f, sC = 0.f, sD = 0.f;
#pragma unroll
    for (int q = 0; q < 16; ++q) {
      float4 Ev = *(const float4*)&s_hs[q*4];
      float4 vv = *(const float4*)&s_aev[q*4];
      sA = fmaf(vv.x, rcpf_(fmaf(Ev.x, P[q*4+0], 1.f)), sA);
      sB = fmaf(vv.y, rcpf_(fmaf(Ev.y, P[q*4+1], 1.f)), sB);
      sC = fmaf(vv.z, rcpf_(fmaf(Ev.z, P[q*4+2], 1.f)), sC);
      sD = fmaf(vv.w, rcpf_(fmaf(Ev.w, P[q*4+3], 1.f)), sD);
    }
    float sc = fmaf(-2.f, (sA+sB)+(sC+sD), vsum);
    float pe = __expf(sc);
    float ws = pe;   // 64 distinct f per wave -> full-wave butterfly
    ws += __shfl_xor(ws,1);  ws += __shfl_xor(ws,2);  ws += __shfl_xor(ws,4);
    ws += __shfl_xor(ws,8);  ws += __shfl_xor(ws,16); ws += __shfl_xor(ws,32);
    if (lane == 0) s_redB[wv] = ws;
    s_xtld[tid] = pe * xtv;   // unnormalized
    __syncthreads();  // b2

    // z[k=tid] = (xtld . eK)*invS + h . eR + eb   (all-register FMA)
    float4 r = *(const float4*)&s_redB[0];
    float invS = rcpf_((r.x + r.y) + (r.z + r.w));
    float a0 = 0.f, a1 = 0.f, a2 = 0.f, a3 = 0.f;
#pragma unroll
    for (int q = 0; q < 64; ++q) {
      float4 x4 = *(const float4*)&s_xtld[q*4];
      a0 = fmaf(x4.x, eKr[q*4+0], a0);
      a1 = fmaf(x4.y, eKr[q*4+1], a1);
      a2 = fmaf(x4.z, eKr[q*4+2], a2);
      a3 = fmaf(x4.w, eKr[q*4+3], a3);
    }
    float h0 = 0.f, h1 = 0.f;
#pragma unroll
    for (int q = 0; q < 16; ++q) {
      float4 h4 = *(const float4*)&s_h[q*4];
      h0 = fmaf(h4.x, eRr[q*4+0], h0); h1 = fmaf(h4.y, eRr[q*4+1], h1);
      h0 = fmaf(h4.z, eRr[q*4+2], h0); h1 = fmaf(h4.w, eRr[q*4+3], h1);
    }
    float v = fmaf((a0+a1)+(a2+a3), invS, (h0+h1) + eb_k);
    float a = (wv == 2) ? tanh_e(v) : sigm(v);
    s_ag[tid] = a;
    __syncthreads();  // b3

    if (tid < 64) {
      float gi = s_ag[tid], gf = s_ag[64+tid], gg = s_ag[128+tid], go = s_ag[192+tid];
      float cn = fmaf(gf, s_c[tid], gi*gg);
      float hn = go * tanh_e(cn);
      s_c[tid] = cn; s_h[tid] = hn; s_xenc[t*68 + tid] = hn;
    }
    __syncthreads();  // b4
  }

  // ================= decoder prologue =================
  for (int i = tid; i < 4096; i += 256) s_w[i] = adW[8192 + i];   // Wd_x
  if (tid < 64) { s_h[tid] = 0.f; s_c[tid] = 0.f; s_yprev[tid] = inb[tid*256 + 255]; }
  __syncthreads();  // d1

  // pd_[i] = exp(2*xe_proj[t'=u4][g4*16+i])  (step-invariant)
  float pd_[16];
  {
    float xe[16];
#pragma unroll
    for (int i = 0; i < 16; ++i) xe[i] = 0.f;
    for (int e = 0; e < 64; ++e) {
      float xv = s_xenc[u4*68 + e];
#pragma unroll
      for (int q = 0; q < 4; ++q) {
        float4 w = *(const float4*)&s_w[e*64 + g4*16 + q*4];
        xe[q*4+0] = fmaf(xv, w.x, xe[q*4+0]);
        xe[q*4+1] = fmaf(xv, w.y, xe[q*4+1]);
        xe[q*4+2] = fmaf(xv, w.z, xe[q*4+2]);
        xe[q*4+3] = fmaf(xv, w.w, xe[q*4+3]);
      }
    }
#pragma unroll
    for (int i = 0; i < 16; ++i) pd_[i] = __expf(2.0f*xe[i]);
  }
  float dKr[64];
#pragma unroll
  for (int j = 0; j < 64; ++j) dKr[j] = dKg[j*256 + tid];
  __syncthreads();  // d2: pd done with Wd_x
  for (int i = tid; i < 4160; i += 256) s_w[i] = fcW[i];
  __syncthreads();  // d3

  // macc[e] = (fcW_ctx @ dK)[e][k];  m2k = fcW_y@dK;  mbk = fcb@dK + db
  float m2k = 0.f, mbk = dbg[tid];
  float macc[64];
#pragma unroll
  for (int e = 0; e < 64; ++e) {
    float c0 = 0.f, c1 = 0.f;
#pragma unroll
    for (int q = 0; q < 16; ++q) {
      float4 w = *(const float4*)&s_w[e*64 + q*4];
      c0 = fmaf(w.x, dKr[q*4+0], c0); c1 = fmaf(w.y, dKr[q*4+1], c1);
      c0 = fmaf(w.z, dKr[q*4+2], c0); c1 = fmaf(w.w, dKr[q*4+3], c1);
    }
    macc[e] = c0 + c1;
  }
#pragma unroll
  for (int q = 0; q < 16; ++q) {
    float4 w = *(const float4*)&s_w[4096 + q*4];   // fcW row 64
    m2k = fmaf(w.x, dKr[q*4+0], m2k); m2k = fmaf(w.y, dKr[q*4+1], m2k);
    m2k = fmaf(w.z, dKr[q*4+2], m2k); m2k = fmaf(w.w, dKr[q*4+3], m2k);
    mbk = fmaf(fcb[q*4+0], dKr[q*4+0], mbk); mbk = fmaf(fcb[q*4+1], dKr[q*4+1], mbk);
    mbk = fmaf(fcb[q*4+2], dKr[q*4+2], mbk); mbk = fmaf(fcb[q*4+3], dKr[q*4+3], mbk);
  }
  // XMr[t] = sum_e xenc[t][e]*macc[e]   (register-resident, dKr/macc die after)
  float XMr[64];
#pragma unroll
  for (int t = 0; t < 64; ++t) {
    float c0 = 0.f, c1 = 0.f;
#pragma unroll
    for (int q = 0; q < 16; ++q) {
      float4 xv = *(const float4*)&s_xenc[t*68 + q*4];
      c0 = fmaf(xv.x, macc[q*4+0], c0); c1 = fmaf(xv.y, macc[q*4+1], c1);
      c0 = fmaf(xv.z, macc[q*4+2], c0); c1 = fmaf(xv.w, macc[q*4+3], c1);
    }
    XMr[t] = c0 + c1;
  }
  float dRr[64];
#pragma unroll
  for (int j = 0; j < 64; ++j) dRr[j] = dRg[j*256 + tid];
  float wdd[16], wdc[16], advr[16];
#pragma unroll
  for (int jj = 0; jj < 16; ++jj) {
    wdd[jj]  = adW[(g4*16 + jj)*64 + u4];
    wdc[jj]  = adW[(64 + g4*16 + jj)*64 + u4];
    advr[jj] = adv[g4*16 + jj];
  }
  float vsumd = 0.f;
#pragma unroll
  for (int i = 0; i < 16; ++i) vsumd += advr[i];
  vsumd += __shfl_xor(vsumd, 1); vsumd += __shfl_xor(vsumd, 2);
  const float adb_u = adb[u4];

  // ================= decoder loop (4 barriers/step) =================
  for (int t = 0; t < 64; ++t) {
    // A
    float p0 = 0.f, p1 = 0.f;
#pragma unroll
    for (int q = 0; q < 4; ++q) {
      float4 h4 = *(const float4*)&s_h[g4*16 + q*4];
      float4 c4 = *(const float4*)&s_c[g4*16 + q*4];
      p0 = fmaf(h4.x, wdd[q*4+0], p0);  p0 = fmaf(h4.y, wdd[q*4+1], p0);
      p0 = fmaf(h4.z, wdd[q*4+2], p0);  p0 = fmaf(h4.w, wdd[q*4+3], p0);
      p1 = fmaf(c4.x, wdc[q*4+0], p1);  p1 = fmaf(c4.y, wdc[q*4+1], p1);
      p1 = fmaf(c4.z, wdc[q*4+2], p1);  p1 = fmaf(c4.w, wdc[q*4+3], p1);
    }
    float p = p0 + p1;
    p += __shfl_xor(p, 1); p += __shfl_xor(p, 2);
    float E = __expf(2.0f*(p + adb_u));
    if (g4 == 0) s_hs[u4] = E;
    __syncthreads();  // b1

    // C: t'=u4, u-slice g4*16..+16
    float sA = 0.f, sB = 0.f;
#pragma unroll
    for (int q = 0; q < 4; ++q) {
      float4 Ev = *(const float4*)&s_hs[g4*16 + q*4];
      sA = fmaf(advr[q*4+0], rcpf_(fmaf(Ev.x, pd_[q*4+0], 1.f)), sA);
      sB = fmaf(advr[q*4+1], rcpf_(fmaf(Ev.y, pd_[q*4+1], 1.f)), sB);
      sA = fmaf(advr[q*4+2], rcpf_(fmaf(Ev.z, pd_[q*4+2], 1.f)), sA);
      sB = fmaf(advr[q*4+3], rcpf_(fmaf(Ev.w, pd_[q*4+3], 1.f)), sB);
    }
    float sacc = sA + sB;
    sacc += __shfl_xor(sacc, 1); sacc += __shfl_xor(sacc, 2);
    float sc = fmaf(-2.f, sacc, vsumd);
    float pe = __expf(sc);
    if (g4 == 0) s_pe[u4] = pe;
    float ws = pe;   // xor{4..32} sums the wave's 16 distinct t' ONCE each
    ws += __shfl_xor(ws,4); ws += __shfl_xor(ws,8);
    ws += __shfl_xor(ws,16); ws += __shfl_xor(ws,32);
    if (lane == 0) s_redB[wv] = ws;
    __syncthreads();  // b2

    // z[k] = invS*(pe.XMr) + d.dRr + y*m2k + mbk   (Sr == S, no extra factor)
    float4 r = *(const float4*)&s_redB[0];
    float invS = rcpf_((r.x + r.y) + (r.z + r.w));
    float q0 = 0.f, q1 = 0.f;
#pragma unroll
    for (int q = 0; q < 16; ++q) {
      float4 pv = *(const float4*)&s_pe[q*4];
      q0 = fmaf(pv.x, XMr[q*4+0], q0); q1 = fmaf(pv.y, XMr[q*4+1], q1);
      q0 = fmaf(pv.z, XMr[q*4+2], q0); q1 = fmaf(pv.w, XMr[q*4+3], q1);
    }
    float r0 = 0.f, r1 = 0.f;
#pragma unroll
    for (int q = 0; q < 16; ++q) {
      float4 h4 = *(const float4*)&s_h[q*4];
      r0 = fmaf(h4.x, dRr[q*4+0], r0); r1 = fmaf(h4.y, dRr[q*4+1], r1);
      r0 = fmaf(h4.z, dRr[q*4+2], r0); r1 = fmaf(h4.w, dRr[q*4+3], r1);
    }
    float v = fmaf(q0+q1, invS, fmaf(s_yprev[t], m2k, (r0+r1) + mbk));
    float a = (wv == 2) ? tanh_e(v) : sigm(v);
    s_ag[tid] = a;
    __syncthreads();  // b3

    if (tid < 64) {
      float gi = s_ag[tid], gf = s_ag[64+tid], gg = s_ag[128+tid], go = s_ag[192+tid];
      float cn = fmaf(gf, s_c[tid], gi*gg);
      s_c[tid] = cn;
      s_h[tid] = go * tanh_e(cn);
    }
    __syncthreads();  // b4
  }

  // final context from last step's pe/S  (Sr == S, no extra factor)
  {
    float4 r = *(const float4*)&s_redB[0];
    float invS = rcpf_((r.x + r.y) + (r.z + r.w));
    float pc = 0.f;
#pragma unroll
    for (int q = 0; q < 16; ++q)
      pc = fmaf(s_pe[g4*16 + q], s_xenc[(g4*16 + q)*68 + u4], pc);
    pc += __shfl_xor(pc, 1); pc += __shfl_xor(pc, 2);
    if (g4 == 0) s_ctx[u4] = pc * invS;
  }
  __syncthreads();

  // epilogue: out = [d_n, ctx] @ fcfW + fcfb   (f = tid)
  {
    float a0 = fcfb[tid], a1 = 0.f, a2 = 0.f, a3 = 0.f;
#pragma unroll
    for (int q = 0; q < 16; ++q) {
      float4 h4 = *(const float4*)&s_h[q*4];
      a0 = fmaf(h4.x, fcfW[(q*4+0)*256 + tid], a0);
      a1 = fmaf(h4.y, fcfW[(q*4+1)*256 + tid], a1);
      a2 = fmaf(h4.z, fcfW[(q*4+2)*256 + tid], a2);
      a3 = fmaf(h4.w, fcfW[(q*4+3)*256 + tid], a3);
      float4 c4 = *(const float4*)&s_ctx[q*4];
      a0 = fmaf(c4.x, fcfW[(64 + q*4+0)*256 + tid], a0);
      a1 = fmaf(c4.y, fcfW[(64 + q*4+1)*256 + tid], a1);
      a2 = fmaf(c4.z, fcfW[(64 + q*4+2)*256 + tid], a2);
      a3 = fmaf(c4.w, fcfW[(64 + q*4+3)*256 + tid], a3);
    }
    out[b*256 + tid] = (a0 + a1) + (a2 + a3);
  }
}

extern "C" void kernel_launch(void* const* d_in, const int* in_sizes, int n_in,
                              void* d_out, int out_size, void* d_ws, size_t ws_size,
                              hipStream_t stream) {
  const float* gin  = (const float*)d_in[0];
  const float* eK   = (const float*)d_in[1];
  const float* eR   = (const float*)d_in[2];
  const float* eb   = (const float*)d_in[3];
  const float* dK   = (const float*)d_in[4];
  const float* dR   = (const float*)d_in[5];
  const float* db   = (const float*)d_in[6];
  const float* aeW  = (const float*)d_in[7];
  const float* aeb  = (const float*)d_in[8];
  const float* aev  = (const float*)d_in[9];
  // d_in[10] attn_e_vb, d_in[14] attn_d_vb: constant shifts, cancel in softmax
  const float* adW  = (const float*)d_in[11];
  const float* adb  = (const float*)d_in[12];
  const float* adv  = (const float*)d_in[13];
  const float* fcW  = (const float*)d_in[15];
  const float* fcb  = (const float*)d_in[16];
  const float* fcfW = (const float*)d_in[17];
  const float* fcfb = (const float*)d_in[18];
  float* out = (float*)d_out;

  const int B = in_sizes[0] / (64*256);
  hipLaunchKernelGGL(darnn_fused, dim3(B), dim3(256), 0, stream,
                     gin, eK, eR, eb, dK, dR, db, aeW, aeb, aev,
                     adW, adb, adv, fcW, fcb, fcfW, fcfb, out);
}